// Round 4
// baseline (140.235 us; speedup 1.0000x reference)
//
#include <hip/hip_runtime.h>
#include <hip/hip_bf16.h>
#include <math.h>

#define C0 8
#define C1 4
#define NCH 20          // C0 + 3*C1
#define NQ 16
#define K3 125
#define G 8
#define RMAX 5.5f
#define EPSL 1e-6f

#define KD1 2048        // gemm1 K = 128 taps * 16 q
#define PHI_N 1048576   // 512 * 2048
#define XTP_N 552960    // 20*1728*16
#define W2_N 20480      // 32*20*32
#define E2C_B 10485760  // bytes per kc chunk of E2: 16*20*512*32*2

#define LDS_SZ 34816    // max(B slab 27648, epilogue 4*8704)

using f32x4 = __attribute__((ext_vector_type(4))) float;
using s16x8 = __attribute__((ext_vector_type(8))) short;

__device__ __forceinline__ float epsf(int i, int m, int j) {
    if (i == m || m == j || i == j) return 0.f;
    return (m == (i + 1) % 3) ? 1.f : -1.f;
}

// ---------------- prep: phi, xtp, w2 (bf16) ----------------
// phi[m=p*32+b][t*16+q]  b = g*4+mi, mi: 0=R, 1..3 = R*u_{z,y,x}; t>=125 zero
// xtp[c][az][ay][ax][q]  zero-padded 12^3
// w2 [o=32pad][c=20][b=32]
__global__ __launch_bounds__(256) void prep_kernel(
    const float* __restrict__ x,
    const float* __restrict__ q_in, const float* __restrict__ q_out,
    const float* __restrict__ w_ss, const float* __restrict__ w_vs,
    const float* __restrict__ w_sv, const float* __restrict__ w_vv0,
    const float* __restrict__ w_vv1,
    __hip_bfloat16* __restrict__ phi, __hip_bfloat16* __restrict__ xtp,
    __hip_bfloat16* __restrict__ w2)
{
    int gid = blockIdx.x * 256 + threadIdx.x;   // exact grid
    if (gid < PHI_N) {
        int col = gid & (KD1 - 1); int m = gid >> 11;
        int t = col >> 4, q = col & 15;
        int p = m >> 5,  b = m & 31;
        int g = b >> 2,  mi = b & 3;
        float val = 0.f;
        if (t < K3) {
            int tz = t / 25, ty = (t / 5) % 5, tx = t % 5;
            float vz = (float)(tz - 2) - (q_out[p*3+0] - q_in[q*3+0]);
            float vy = (float)(ty - 2) - (q_out[p*3+1] - q_in[q*3+1]);
            float vx = (float)(tx - 2) - (q_out[p*3+2] - q_in[q*3+2]);
            float r  = sqrtf(vz*vz + vy*vy + vx*vx);
            float inv = (r > EPSL) ? (1.0f / r) : 0.0f;
            const float sigma = RMAX / (float)(G - 1);
            float d = (r - (RMAX * (float)g / (float)(G - 1))) / sigma;
            float Rg = expf(-0.5f * d * d);
            float u = (mi == 1) ? vz*inv : ((mi == 2) ? vy*inv : vx*inv);
            val = (mi == 0) ? Rg : Rg * u;
        }
        phi[gid] = __float2bfloat16(val);
    } else if (gid < PHI_N + XTP_N) {
        int g2 = gid - PHI_N;
        int q = g2 & 15; int r = g2 >> 4;
        int ax = r % 12; r /= 12;
        int ay = r % 12; r /= 12;
        int az = r % 12; int c = r / 12;
        int iz = az - 2, iy = ay - 2, ix = ax - 2;
        bool valid = ((unsigned)iz < 8u) & ((unsigned)iy < 8u) & ((unsigned)ix < 8u);
        float v = valid ? x[((c * NQ + q) << 9) + (iz << 6) + (iy << 3) + ix] : 0.f;
        xtp[g2] = __float2bfloat16(v);
    } else {
        int id = gid - (PHI_N + XTP_N);
        int b = id & 31; int r = id >> 5;
        int c = r % NCH; int o = r / NCH;
        int g = b >> 2,  mi = b & 3;
        float val = 0.f;
        if (o < NCH) {
            if (o < C0) {
                if (c < C0) { if (mi == 0) val = w_ss[(o * C0 + c) * G + g]; }
                else { int cv = (c - C0) / 3, j = (c - C0) % 3;
                       if (mi == 1 + j) val = w_sv[(o * C1 + cv) * G + g]; }
            } else {
                int ov = (o - C0) / 3, i = (o - C0) % 3;
                if (c < C0) { if (mi == 1 + i) val = w_vs[(ov * C0 + c) * G + g]; }
                else {
                    int cv = (c - C0) / 3, j = (c - C0) % 3;
                    if (mi == 0) { if (i == j) val = w_vv0[(ov * C1 + cv) * G + g]; }
                    else val = 0.7071067811865476f * w_vv1[(ov * C1 + cv) * G + g]
                               * epsf(i, mi - 1, j);
                }
            }
        }
        w2[id] = __float2bfloat16(val);
    }
}

// ---------------- gemm1: B-resident LDS (swizzled) + asm-pipelined direct-global A ----------------
// grid 640 = kc(2) x pg(4: 128 m-rows = 4 p's) x c(20) x zq(4: 128 z)
// block 256 thr = 2x2 waves of 64x64; 16 chunks of 64 k-elems (4 taps)
// A loads: volatile asm global_load_dwordx4, double-buffered, counted vmcnt(8)
// (never 0 in steady state) so 8 loads stay in flight under each compute phase.
__global__ __launch_bounds__(256, 2) void gemm1_kernel(
    const char* __restrict__ phi_b, const char* __restrict__ xtp_b,
    char* __restrict__ E2_b)
{
    __shared__ __align__(16) char lds[LDS_SZ];

    int tid = threadIdx.x;
    int wave = tid >> 6, lane = tid & 63;
    int row = lane & 15, quad = lane >> 4;
    int wi = wave >> 1, wj = wave & 1;
    int hi = quad >> 1;

    int bi = blockIdx.x;                 // 640
    int kc = bi / 320;
    int r  = bi - kc * 320;
    int pg = r / 80;
    int r2 = r - pg * 80;
    int c  = r2 >> 2;
    int zq = r2 & 3;

    // ---- B slab: xtp[c][az = 2zq .. 2zq+5][ay][ax][q], 27648 B, XOR-swizzled ----
    {
        const char* src = xtp_b + c * 55296 + zq * 9216;
        for (int i = tid; i < 1728; i += 256) {
            int d = (i * 16) ^ (((i >> 1) & 7) << 4);
            *(s16x8*)(lds + d) = *(const s16x8*)(src + i * 16);
        }
    }

    // ---- A bases: frag addr = (pg*128 + wi*64 + mt*16 + row)*4096 + kc*2048
    //               + j*128 + st*64 + quad*16  (validated in round 2) ----
    const char* abase = phi_b + (size_t)(pg * 128 + wi * 64 + row) * 4096
                        + kc * 2048 + quad * 16;
    const char* ap[4];
    #pragma unroll
    for (int m = 0; m < 4; ++m) ap[m] = abase + m * 65536;

    // per-lane B LDS pre-offsets (linear; swizzle applied at read)
    int bpre[4];
    #pragma unroll
    for (int nt = 0; nt < 4; ++nt) {
        int zl = wj * 64 + nt * 16 + row;
        int zz = zl >> 6, zy = (zl >> 3) & 7, zx = zl & 7;
        bpre[nt] = (zz * 144 + zy * 12 + zx) * 32 + (quad & 1) * 16;
    }

    f32x4 acc[4][4];
    #pragma unroll
    for (int i = 0; i < 4; ++i)
        #pragma unroll
        for (int j = 0; j < 4; ++j) acc[i][j] = (f32x4){0.f, 0.f, 0.f, 0.f};

    __syncthreads();   // B slab visible; the ONLY barrier before the epilogue

    // asm loads are NOT scoreboard-tracked by the compiler: the counted
    // vmcnt + sched_barrier(0) below are correctness-required (rule #18).
    #define ALOAD(Adst, jj) do {                                              \
        _Pragma("unroll")                                                     \
        for (int s_ = 0; s_ < 2; ++s_)                                        \
            _Pragma("unroll")                                                 \
            for (int m_ = 0; m_ < 4; ++m_) {                                  \
                const char* a_ = ap[m_] + (jj) * 128 + s_ * 64;               \
                asm volatile("global_load_dwordx4 %0, %1, off"                \
                    : "=v"(Adst[s_ * 4 + m_]) : "v"(a_));                     \
            }                                                                 \
    } while (0)

    #define WAITV(N) do {                                                     \
        asm volatile("s_waitcnt vmcnt(" #N ")" ::: "memory");                 \
        __builtin_amdgcn_sched_barrier(0);                                    \
    } while (0)

    #define COMPUTE(Asrc, jj) do {                                            \
        int toff_[4];                                                         \
        _Pragma("unroll")                                                     \
        for (int tt_ = 0; tt_ < 4; ++tt_) {                                   \
            int t_ = kc * 64 + (jj) * 4 + tt_; if (t_ > 124) t_ = 124;        \
            int tz_ = t_ / 25, trm_ = t_ - tz_ * 25;                          \
            int ty_ = trm_ / 5, tx_ = trm_ - ty_ * 5;                         \
            toff_[tt_] = (tz_ * 144 + ty_ * 12 + tx_) * 32;                   \
        }                                                                     \
        _Pragma("unroll")                                                     \
        for (int st_ = 0; st_ < 2; ++st_) {                                   \
            s16x8 bf_[4];                                                     \
            int tsel_ = toff_[st_ * 2 + hi];                                  \
            _Pragma("unroll")                                                 \
            for (int nt_ = 0; nt_ < 4; ++nt_) {                               \
                int ba_ = bpre[nt_] + tsel_;                                  \
                ba_ ^= ((ba_ >> 5) & 7) << 4;                                 \
                bf_[nt_] = *(const s16x8*)(lds + ba_);                        \
            }                                                                 \
            _Pragma("unroll")                                                 \
            for (int mt_ = 0; mt_ < 4; ++mt_)                                 \
                _Pragma("unroll")                                             \
                for (int nt_ = 0; nt_ < 4; ++nt_)                             \
                    acc[mt_][nt_] = __builtin_amdgcn_mfma_f32_16x16x32_bf16(  \
                        Asrc[st_ * 4 + mt_], bf_[nt_], acc[mt_][nt_], 0, 0, 0);\
        }                                                                     \
    } while (0)

    s16x8 A0[8], A1[8];
    ALOAD(A0, 0);                       // 8 outstanding
    for (int j = 0; j < 14; j += 2) {
        ALOAD(A1, j + 1);               // 16 outstanding
        WAITV(8);                       // A0 ready; A1's 8 stay in flight
        COMPUTE(A0, j);
        ALOAD(A0, j + 2);               // 16 outstanding
        WAITV(8);                       // A1 ready; A0's 8 stay in flight
        COMPUTE(A1, j + 1);
    }
    // peeled final pair (j = 14, 15)
    ALOAD(A1, 15);
    WAITV(8);                           // A0(14) ready
    COMPUTE(A0, 14);
    WAITV(0);                           // drain: A1(15) ready
    COMPUTE(A1, 15);

    #undef ALOAD
    #undef WAITV
    #undef COMPUTE

    __syncthreads();   // all B reads done; LDS reusable for epilogue transpose

    // ---- epilogue: wave-private LDS transpose -> 1KB-contiguous stores ----
    int wbase = wave * 8704;                     // 64 zl x 136 B
    #pragma unroll
    for (int mt = 0; mt < 4; ++mt) {
        #pragma unroll
        for (int nt = 0; nt < 4; ++nt) {
            int zl = nt * 16 + row;
            union { unsigned long long u; __hip_bfloat16 h[4]; } pk;
            pk.h[0] = __float2bfloat16(acc[mt][nt][0]);
            pk.h[1] = __float2bfloat16(acc[mt][nt][1]);
            pk.h[2] = __float2bfloat16(acc[mt][nt][2]);
            pk.h[3] = __float2bfloat16(acc[mt][nt][3]);
            *(unsigned long long*)(lds + wbase + zl * 136 + (mt * 16 + quad * 4) * 2) = pk.u;
        }
    }
    // wave-local exchange: no barrier needed
    char* Ek = E2_b + (size_t)kc * E2C_B;
    int pbase = pg * 4 + wi * 2;
    #pragma unroll
    for (int it = 0; it < 8; ++it) {
        int item = lane + it * 64;
        int piece = item & 3;
        int zl = (item >> 2) & 63;
        int h  = item >> 8;
        s16x8 v = *(const s16x8*)(lds + wbase + zl * 136 + h * 64 + piece * 16);
        int p = pbase + h;
        int z = zq * 128 + wj * 64 + zl;
        *(s16x8*)(Ek + ((size_t)((p * NCH + c) << 9) + z) * 64 + piece * 16) = v;
    }
}

// ---------------- gemm2: out[o][p][z] = bias + sum_{kc,c,b} w2 * E2  (direct store) ----------------
// 256 blocks x 128 thr = p(16) x zb(16); full K=1280 chain (40 MFMA-pairs), no atomics
__global__ __launch_bounds__(128) void gemm2_kernel(
    const char* __restrict__ w2_b, const char* __restrict__ E2_b,
    const float* __restrict__ bias, float* __restrict__ out)
{
    int tid = threadIdx.x;
    int wave = tid >> 6, lane = tid & 63;
    int row = lane & 15, quad = lane >> 4;
    int bi = blockIdx.x;                 // 256
    int p  = bi >> 4;
    int zb = bi & 15;
    int z  = zb * 32 + wave * 16 + row;

    const char* bbase = E2_b + (size_t)p * 655360 + (size_t)z * 64 + quad * 16;

    f32x4 acc[2];
    acc[0] = (f32x4){0.f, 0.f, 0.f, 0.f};
    acc[1] = (f32x4){0.f, 0.f, 0.f, 0.f};

    #pragma unroll
    for (int kc = 0; kc < 2; ++kc) {
        #pragma unroll 5
        for (int cc = 0; cc < 20; ++cc) {
            s16x8 a0 = *(const s16x8*)(w2_b + (row)      * 1280 + cc * 64 + quad * 16);
            s16x8 a1 = *(const s16x8*)(w2_b + (16 + row) * 1280 + cc * 64 + quad * 16);
            s16x8 b  = *(const s16x8*)(bbase + (size_t)kc * E2C_B + (size_t)cc * 32768);
            acc[0] = __builtin_amdgcn_mfma_f32_16x16x32_bf16(a0, b, acc[0], 0, 0, 0);
            acc[1] = __builtin_amdgcn_mfma_f32_16x16x32_bf16(a1, b, acc[1], 0, 0, 0);
        }
    }

    #pragma unroll
    for (int mt = 0; mt < 2; ++mt)
        #pragma unroll
        for (int ri = 0; ri < 4; ++ri) {
            int o = mt * 16 + quad * 4 + ri;
            if (o < NCH) {
                float v = acc[mt][ri];
                if (o < C0) v += bias[o];
                out[((o * NQ + p) << 9) + z] = v;
            }
        }
}

extern "C" void kernel_launch(void* const* d_in, const int* in_sizes, int n_in,
                              void* d_out, int out_size, void* d_ws, size_t ws_size,
                              hipStream_t stream) {
    const float* x     = (const float*)d_in[0];
    const float* q_in  = (const float*)d_in[1];
    const float* q_out = (const float*)d_in[2];
    const float* w_ss  = (const float*)d_in[3];
    const float* w_vs  = (const float*)d_in[4];
    const float* w_sv  = (const float*)d_in[5];
    const float* w_vv0 = (const float*)d_in[6];
    const float* w_vv1 = (const float*)d_in[7];
    const float* bias  = (const float*)d_in[8];
    float* out = (float*)d_out;

    char* ws = (char*)d_ws;
    __hip_bfloat16* phi = (__hip_bfloat16*)(ws + 0);          //  2,097,152 B
    __hip_bfloat16* xtp = (__hip_bfloat16*)(ws + 2097152);    //  1,105,920 B
    __hip_bfloat16* w2  = (__hip_bfloat16*)(ws + 3203072);    //     40,960 B
    char*           E2  = (char*)(ws + 3244032);              // 20,971,520 B (total 24.2 MB)

    const int PREP_N = PHI_N + XTP_N + W2_N;                  // 1,622,016 = 6336*256
    hipLaunchKernelGGL(prep_kernel, dim3(PREP_N / 256), dim3(256), 0, stream,
                       x, q_in, q_out, w_ss, w_vs, w_sv, w_vv0, w_vv1,
                       phi, xtp, w2);
    hipLaunchKernelGGL(gemm1_kernel, dim3(640), dim3(256), 0, stream,
                       (const char*)phi, (const char*)xtp, E2);
    hipLaunchKernelGGL(gemm2_kernel, dim3(256), dim3(128), 0, stream,
                       (const char*)w2, (const char*)E2, bias, out);
}

// Round 5
// 115.405 us; speedup vs baseline: 1.2152x; 1.2152x over previous
//
#include <hip/hip_runtime.h>
#include <hip/hip_bf16.h>
#include <math.h>

#define C0 8
#define C1 4
#define NCH 20          // C0 + 3*C1
#define NQ 16
#define K3 125
#define G 8
#define RMAX 5.5f
#define EPSL 1e-6f

#define KD1 2048        // gemm1 K = 128 taps * 16 q
#define PHI_N 1048576   // 512 * 2048
#define XTP_N 552960    // 20*1728*16
#define W2_N 20480      // 32*20*32
#define E2C_B 10485760  // bytes per kc chunk of E2: 16*20*512*32*2

#define LDS_A 16384     // 128 rows * 128 B, XOR-swizzled layout (DMA-written)
#define LDS_B 27648     // 6*12*12*16 bf16 slab at offset 16384
#define LDS_SZ 44032    // >= epilogue 4*8704 = 34816

using f32x4 = __attribute__((ext_vector_type(4))) float;
using s16x8 = __attribute__((ext_vector_type(8))) short;

typedef const __attribute__((address_space(1))) unsigned int gq_t;
typedef __attribute__((address_space(3))) unsigned int lq_t;

__device__ __forceinline__ float epsf(int i, int m, int j) {
    if (i == m || m == j || i == j) return 0.f;
    return (m == (i + 1) % 3) ? 1.f : -1.f;
}

// ---------------- prep: phi, xtp, w2 (bf16) ----------------
// phi[m=p*32+b][t*16+q]  b = g*4+mi, mi: 0=R, 1..3 = R*u_{z,y,x}; t>=125 zero
// xtp[c][az][ay][ax][q]  zero-padded 12^3
// w2 [o=32pad][c=20][b=32]
__global__ __launch_bounds__(256) void prep_kernel(
    const float* __restrict__ x,
    const float* __restrict__ q_in, const float* __restrict__ q_out,
    const float* __restrict__ w_ss, const float* __restrict__ w_vs,
    const float* __restrict__ w_sv, const float* __restrict__ w_vv0,
    const float* __restrict__ w_vv1,
    __hip_bfloat16* __restrict__ phi, __hip_bfloat16* __restrict__ xtp,
    __hip_bfloat16* __restrict__ w2)
{
    int gid = blockIdx.x * 256 + threadIdx.x;   // exact grid
    if (gid < PHI_N) {
        int col = gid & (KD1 - 1); int m = gid >> 11;
        int t = col >> 4, q = col & 15;
        int p = m >> 5,  b = m & 31;
        int g = b >> 2,  mi = b & 3;
        float val = 0.f;
        if (t < K3) {
            int tz = t / 25, ty = (t / 5) % 5, tx = t % 5;
            float vz = (float)(tz - 2) - (q_out[p*3+0] - q_in[q*3+0]);
            float vy = (float)(ty - 2) - (q_out[p*3+1] - q_in[q*3+1]);
            float vx = (float)(tx - 2) - (q_out[p*3+2] - q_in[q*3+2]);
            float r  = sqrtf(vz*vz + vy*vy + vx*vx);
            float inv = (r > EPSL) ? (1.0f / r) : 0.0f;
            const float sigma = RMAX / (float)(G - 1);
            float d = (r - (RMAX * (float)g / (float)(G - 1))) / sigma;
            float Rg = expf(-0.5f * d * d);
            float u = (mi == 1) ? vz*inv : ((mi == 2) ? vy*inv : vx*inv);
            val = (mi == 0) ? Rg : Rg * u;
        }
        phi[gid] = __float2bfloat16(val);
    } else if (gid < PHI_N + XTP_N) {
        int g2 = gid - PHI_N;
        int q = g2 & 15; int r = g2 >> 4;
        int ax = r % 12; r /= 12;
        int ay = r % 12; r /= 12;
        int az = r % 12; int c = r / 12;
        int iz = az - 2, iy = ay - 2, ix = ax - 2;
        bool valid = ((unsigned)iz < 8u) & ((unsigned)iy < 8u) & ((unsigned)ix < 8u);
        float v = valid ? x[((c * NQ + q) << 9) + (iz << 6) + (iy << 3) + ix] : 0.f;
        xtp[g2] = __float2bfloat16(v);
    } else {
        int id = gid - (PHI_N + XTP_N);
        int b = id & 31; int r = id >> 5;
        int c = r % NCH; int o = r / NCH;
        int g = b >> 2,  mi = b & 3;
        float val = 0.f;
        if (o < NCH) {
            if (o < C0) {
                if (c < C0) { if (mi == 0) val = w_ss[(o * C0 + c) * G + g]; }
                else { int cv = (c - C0) / 3, j = (c - C0) % 3;
                       if (mi == 1 + j) val = w_sv[(o * C1 + cv) * G + g]; }
            } else {
                int ov = (o - C0) / 3, i = (o - C0) % 3;
                if (c < C0) { if (mi == 1 + i) val = w_vs[(ov * C0 + c) * G + g]; }
                else {
                    int cv = (c - C0) / 3, j = (c - C0) % 3;
                    if (mi == 0) { if (i == j) val = w_vv0[(ov * C1 + cv) * G + g]; }
                    else val = 0.7071067811865476f * w_vv1[(ov * C1 + cv) * G + g]
                               * epsf(i, mi - 1, j);
                }
            }
        }
        w2[id] = __float2bfloat16(val);
    }
}

// ---------------- gemm1: A via global_load_lds DMA (pre-swizzled src), B-resident LDS ----------------
// grid 640 = kc(2) x pg(4: 128 m-rows = 4 p's) x c(20) x zq(4: 128 z)
// block 256 thr = 2x2 waves of 64x64; 16 chunks of 64 k-elems (4 taps)
// A LDS layout: linear dest; element at LDS byte d is phi byte (d ^ ((d>>7&7)<<4))
// -> read side applies the same XOR; af bank pattern becomes uniform (conflict-free).
__global__ __launch_bounds__(256, 3) void gemm1_kernel(
    const char* __restrict__ phi_b, const char* __restrict__ xtp_b,
    char* __restrict__ E2_b)
{
    __shared__ __align__(16) char lds[LDS_SZ];

    int tid = threadIdx.x;
    int wave = tid >> 6, lane = tid & 63;
    int row = lane & 15, quad = lane >> 4;
    int wi = wave >> 1, wj = wave & 1;
    int hi = quad >> 1;

    int bi = blockIdx.x;                 // 640
    int kc = bi / 320;
    int r  = bi - kc * 320;
    int pg = r / 80;
    int r2 = r - pg * 80;
    int c  = r2 >> 2;
    int zq = r2 & 3;

    // ---- B slab: xtp[c][az = 2zq .. 2zq+5][ay][ax][q], 27648 B, XOR-swizzled ----
    {
        const char* src = xtp_b + c * 55296 + zq * 9216;
        for (int i = tid; i < 1728; i += 256) {
            int d = (i * 16) ^ (((i >> 1) & 7) << 4);
            *(s16x8*)(lds + LDS_A + d) = *(const s16x8*)(src + i * 16);
        }
    }

    // ---- A DMA source pointers: wave chunk i covers LDS [ (wave*4+i)*1024, +1024 ).
    // lane's 16B dest d = chunk*1024 + lane*16; source element dd = d ^ ((d>>7&7)<<4)
    // -> global row = pg*128 + wave*32 + i*8 + (lane>>3), col-slot = (lane&7)^((lane>>3)&7).
    const char* gA[4];
    {
        int lrow = lane >> 3;
        int cslot = (lane & 7) ^ (lrow & 7);
        #pragma unroll
        for (int i = 0; i < 4; ++i)
            gA[i] = phi_b + (size_t)(pg * 128 + wave * 32 + i * 8 + lrow) * 4096
                    + kc * 2048 + cslot * 16;
    }
    int arx = (row & 7) << 4;            // af read-side XOR key

    // per-lane B LDS pre-offsets (linear; swizzle applied at read; base 16384 has bits 5-7 clear)
    int bpre[4];
    #pragma unroll
    for (int nt = 0; nt < 4; ++nt) {
        int zl = wj * 64 + nt * 16 + row;
        int zz = zl >> 6, zy = (zl >> 3) & 7, zx = zl & 7;
        bpre[nt] = (zz * 144 + zy * 12 + zx) * 32 + (quad & 1) * 16;
    }

    f32x4 acc[4][4];
    #pragma unroll
    for (int i = 0; i < 4; ++i)
        #pragma unroll
        for (int j = 0; j < 4; ++j) acc[i][j] = (f32x4){0.f, 0.f, 0.f, 0.f};

    for (int j = 0; j < 16; ++j) {
        __syncthreads();                 // (a) all waves done reading A(j-1); B visible (j=0)
        #pragma unroll
        for (int i = 0; i < 4; ++i)
            __builtin_amdgcn_global_load_lds(
                (gq_t*)(gA[i] + j * 128),
                (lq_t*)(lds + (wave * 4 + i) * 1024), 16, 0, 0);
        __syncthreads();                 // (b) drain: A(j) visible to all waves

        int toff[4];
        #pragma unroll
        for (int tt = 0; tt < 4; ++tt) {
            int t = kc * 64 + j * 4 + tt; if (t > 124) t = 124;  // pad taps: phi=0
            int tz = t / 25, trm = t - tz * 25;
            int ty = trm / 5, tx = trm - ty * 5;
            toff[tt] = (tz * 144 + ty * 12 + tx) * 32;
        }
        #pragma unroll
        for (int st = 0; st < 2; ++st) {
            s16x8 af[4], bf[4];
            #pragma unroll
            for (int mt = 0; mt < 4; ++mt) {
                int aa = ((wi * 64 + mt * 16 + row) * 128 + (st * 4 + quad) * 16) ^ arx;
                af[mt] = *(const s16x8*)(lds + aa);
            }
            int tsel = toff[st * 2 + hi];
            #pragma unroll
            for (int nt = 0; nt < 4; ++nt) {
                int ba = bpre[nt] + tsel;
                ba ^= ((ba >> 5) & 7) << 4;
                bf[nt] = *(const s16x8*)(lds + LDS_A + ba);
            }
            #pragma unroll
            for (int mt = 0; mt < 4; ++mt)
                #pragma unroll
                for (int nt = 0; nt < 4; ++nt)
                    acc[mt][nt] = __builtin_amdgcn_mfma_f32_16x16x32_bf16(
                        af[mt], bf[nt], acc[mt][nt], 0, 0, 0);
        }
    }
    __syncthreads();                     // all compute done; LDS reusable

    // ---- epilogue: wave-private LDS transpose -> 1KB-contiguous stores ----
    int wbase = wave * 8704;                     // 64 zl x 136 B
    #pragma unroll
    for (int mt = 0; mt < 4; ++mt) {
        #pragma unroll
        for (int nt = 0; nt < 4; ++nt) {
            int zl = nt * 16 + row;
            union { unsigned long long u; __hip_bfloat16 h[4]; } pk;
            pk.h[0] = __float2bfloat16(acc[mt][nt][0]);
            pk.h[1] = __float2bfloat16(acc[mt][nt][1]);
            pk.h[2] = __float2bfloat16(acc[mt][nt][2]);
            pk.h[3] = __float2bfloat16(acc[mt][nt][3]);
            *(unsigned long long*)(lds + wbase + zl * 136 + (mt * 16 + quad * 4) * 2) = pk.u;
        }
    }
    // wave-local exchange: no barrier needed
    char* Ek = E2_b + (size_t)kc * E2C_B;
    int pbase = pg * 4 + wi * 2;
    #pragma unroll
    for (int it = 0; it < 8; ++it) {
        int item = lane + it * 64;
        int piece = item & 3;
        int zl = (item >> 2) & 63;
        int h  = item >> 8;
        s16x8 v = *(const s16x8*)(lds + wbase + zl * 136 + h * 64 + piece * 16);
        int p = pbase + h;
        int z = zq * 128 + wj * 64 + zl;
        *(s16x8*)(Ek + ((size_t)((p * NCH + c) << 9) + z) * 64 + piece * 16) = v;
    }
}

// ---------------- gemm2: out[o][p][z] = bias + sum_{kc,c,b} w2 * E2  (direct store) ----------------
// 256 blocks x 128 thr = p(16) x zb(16); full K=1280 chain (40 MFMA-pairs), no atomics
__global__ __launch_bounds__(128) void gemm2_kernel(
    const char* __restrict__ w2_b, const char* __restrict__ E2_b,
    const float* __restrict__ bias, float* __restrict__ out)
{
    int tid = threadIdx.x;
    int wave = tid >> 6, lane = tid & 63;
    int row = lane & 15, quad = lane >> 4;
    int bi = blockIdx.x;                 // 256
    int p  = bi >> 4;
    int zb = bi & 15;
    int z  = zb * 32 + wave * 16 + row;

    const char* bbase = E2_b + (size_t)p * 655360 + (size_t)z * 64 + quad * 16;

    f32x4 acc[2];
    acc[0] = (f32x4){0.f, 0.f, 0.f, 0.f};
    acc[1] = (f32x4){0.f, 0.f, 0.f, 0.f};

    #pragma unroll
    for (int kc = 0; kc < 2; ++kc) {
        #pragma unroll 5
        for (int cc = 0; cc < 20; ++cc) {
            s16x8 a0 = *(const s16x8*)(w2_b + (row)      * 1280 + cc * 64 + quad * 16);
            s16x8 a1 = *(const s16x8*)(w2_b + (16 + row) * 1280 + cc * 64 + quad * 16);
            s16x8 b  = *(const s16x8*)(bbase + (size_t)kc * E2C_B + (size_t)cc * 32768);
            acc[0] = __builtin_amdgcn_mfma_f32_16x16x32_bf16(a0, b, acc[0], 0, 0, 0);
            acc[1] = __builtin_amdgcn_mfma_f32_16x16x32_bf16(a1, b, acc[1], 0, 0, 0);
        }
    }

    #pragma unroll
    for (int mt = 0; mt < 2; ++mt)
        #pragma unroll
        for (int ri = 0; ri < 4; ++ri) {
            int o = mt * 16 + quad * 4 + ri;
            if (o < NCH) {
                float v = acc[mt][ri];
                if (o < C0) v += bias[o];
                out[((o * NQ + p) << 9) + z] = v;
            }
        }
}

extern "C" void kernel_launch(void* const* d_in, const int* in_sizes, int n_in,
                              void* d_out, int out_size, void* d_ws, size_t ws_size,
                              hipStream_t stream) {
    const float* x     = (const float*)d_in[0];
    const float* q_in  = (const float*)d_in[1];
    const float* q_out = (const float*)d_in[2];
    const float* w_ss  = (const float*)d_in[3];
    const float* w_vs  = (const float*)d_in[4];
    const float* w_sv  = (const float*)d_in[5];
    const float* w_vv0 = (const float*)d_in[6];
    const float* w_vv1 = (const float*)d_in[7];
    const float* bias  = (const float*)d_in[8];
    float* out = (float*)d_out;

    char* ws = (char*)d_ws;
    __hip_bfloat16* phi = (__hip_bfloat16*)(ws + 0);          //  2,097,152 B
    __hip_bfloat16* xtp = (__hip_bfloat16*)(ws + 2097152);    //  1,105,920 B
    __hip_bfloat16* w2  = (__hip_bfloat16*)(ws + 3203072);    //     40,960 B
    char*           E2  = (char*)(ws + 3244032);              // 20,971,520 B (total 24.2 MB)

    const int PREP_N = PHI_N + XTP_N + W2_N;                  // 1,622,016 = 6336*256
    hipLaunchKernelGGL(prep_kernel, dim3(PREP_N / 256), dim3(256), 0, stream,
                       x, q_in, q_out, w_ss, w_vs, w_sv, w_vv0, w_vv1,
                       phi, xtp, w2);
    hipLaunchKernelGGL(gemm1_kernel, dim3(640), dim3(256), 0, stream,
                       (const char*)phi, (const char*)xtp, E2);
    hipLaunchKernelGGL(gemm2_kernel, dim3(256), dim3(128), 0, stream,
                       (const char*)w2, (const char*)E2, bias, out);
}